// Round 3
// baseline (511.753 us; speedup 1.0000x reference)
//
#include <hip/hip_runtime.h>
#include <hip/hip_bf16.h>
#include <cstdint>
#include <cstddef>

// ---------------------------------------------------------------------------
// HeteroGNN (2-layer hetero GAT) on MI355X, gfx950.  Round 14.
//  - r13 post-mortem: conv1 gather FETCH did NOT drop with smaller tables ->
//    binding cache is the 4MB/XCD L2; gather accepted at its ceiling (~84us).
//    The regression vs r11 was serial CSR machinery + lost overlap.
//  - DIRECT-ATOMIC CSR: global atomicAdd degree hist (merged into A-kernel),
//    200K-wide scans (was 418K), scatter writes sw[] at final CSR position
//    via cursor atomics with score+exp fused.  k_finalize, ebuf, histM/histS
//    all eliminated.  Edge order within dst now arbitrary (sum commutes).
//  - FUSED conv1-postproj + conv2-proj: stage1 MFMA -> lrelu -> LDS
//    transpose -> stage2 MFMA + scores.  hp2/hb2 intermediates never hit
//    global (-38MB traffic, -1 launch).
//  - Kept from r13: commuted conv1 (raw-table gather -> aggregate ->
//    postproj), k_fv folded score vectors (now also zeroes deg[]).
// ---------------------------------------------------------------------------

typedef __attribute__((ext_vector_type(8))) short short8;   // 8 bf16 (4 VGPR)
typedef __attribute__((ext_vector_type(4))) float f32x4;    // MFMA acc
typedef unsigned int u32;
typedef __hip_bfloat16 bf16;

#define CHUNKE 4096         // edges per block in streaming edge passes

static __device__ __forceinline__ float ldf(const void* p, int i, int bf) {
    return bf ? __bfloat162float(((const bf16*)p)[i]) : ((const float*)p)[i];
}

static __device__ __forceinline__ short f2bs(float f) {
    bf16 h = __float2bfloat16(f);
    return *reinterpret_cast<short*>(&h);
}
static __device__ __forceinline__ float bs2f(short s) {
    bf16 h = *reinterpret_cast<bf16*>(&s);
    return __bfloat162float(h);
}
static __device__ __forceinline__ float lo16(u32 u) { return bs2f((short)(u & 0xffffu)); }
static __device__ __forceinline__ float hi16(u32 u) { return bs2f((short)(u >> 16)); }
static __device__ __forceinline__ u32 pack2(float x, float y) {
    return (u32)(unsigned short)f2bs(x) | ((u32)(unsigned short)f2bs(y) << 16);
}
static __device__ __forceinline__ float sel4(const float* a, int i) {
    return i == 0 ? a[0] : i == 1 ? a[1] : i == 2 ? a[2] : a[3];
}
static __device__ __forceinline__ float lrelu2(float x) { return x > 0.f ? x : 0.2f * x; }

// per-block inline dtype probe (4 KB of x_b, L2-hot after first block)
static __device__ __forceinline__ int probe_bf(const unsigned* __restrict__ w, int* cnt) {
    if (threadIdx.x == 0) *cnt = 0;
    __syncthreads();
    int c = 0;
#pragma unroll
    for (int j = 0; j < 4; ++j) {
        unsigned u = w[threadIdx.x * 4 + j];
        unsigned e = (u >> 7) & 0xffu;
        c += (e >= 100u && e <= 145u) ? 1 : 0;
    }
    atomicAdd(cnt, c);
    __syncthreads();
    int r = (*cnt > 614) ? 1 : 0;
    __syncthreads();
    return r;
}

// ---- A0: folded score vectors (block 0) + deg[] zeroing (other blocks) ----
__global__ __launch_bounds__(256) void k_fv(
    const unsigned* __restrict__ probe_w, int* __restrict__ flag,
    const void* W_bb1, const void* as_bb1, const void* ad_bb1,
    const void* Ws_bp1, const void* as_bp1,
    const void* W_pp1, const void* as_pp1, const void* ad_pp1,
    const void* Wd_bp1, const void* ad_bp1,
    float* __restrict__ FVg, int* __restrict__ deg, int NALL)
{
    __shared__ int cnt;
    if (blockIdx.x > 0) {
        int stride = ((int)gridDim.x - 1) * 256;
        for (int i = ((int)blockIdx.x - 1) * 256 + threadIdx.x; i < NALL; i += stride)
            deg[i] = 0;
        return;
    }
    int bf = probe_bf(probe_w, &cnt);
    if (threadIdx.x == 0) *flag = bf;
    int lane = threadIdx.x & 63, wv = threadIdx.x >> 6;
    const void* Ws[6] = { W_bb1, W_bb1, Ws_bp1, W_pp1, W_pp1, Wd_bp1 };
    const void* av[6] = { as_bb1, ad_bb1, as_bp1, as_pp1, ad_pp1, ad_bp1 };
#pragma unroll
    for (int v = 0; v < 6; ++v) {
        float a = ldf(av[v], lane, bf);
        for (int k = wv; k < 64; k += 4) {
            float p = ldf(Ws[v], k * 64 + lane, bf) * a;   // coalesced row read
#pragma unroll
            for (int off = 1; off < 64; off <<= 1) p += __shfl_xor(p, off);
            if (lane == 0) FVg[v * 64 + k] = p;
        }
    }
}

// ---- MFMA input projection body + fused conv1 score epilogue --------------
template <int CIN>
static __device__ __forceinline__ void in_proj_body(
    short* WT, float* bl, float* FV, int bid,
    const void* __restrict__ X, const void* __restrict__ W, const void* __restrict__ B,
    const float* __restrict__ FVg,
    bf16* __restrict__ Y,
    float* __restrict__ S0, float* __restrict__ S1v, float* __restrict__ S2v,
    int M, int bf)
{
    constexpr int KP = 40;
    for (int i = threadIdx.x; i < 64 * CIN; i += 256) {
        int n = i / CIN, k = i - n * CIN;
        WT[n * KP + k] = f2bs(ldf(W, k * 64 + n, bf));
    }
    if (threadIdx.x < 64) bl[threadIdx.x] = ldf(B, threadIdx.x, bf);
    if (threadIdx.x < 192) FV[threadIdx.x] = FVg[threadIdx.x];   // L2-hot
    __syncthreads();

    int lane = threadIdx.x & 63;
    int wv   = threadIdx.x >> 6;
    int m = lane & 15, quad = lane >> 4;
    int row0 = (bid * 4 + wv) * 16;
    if (row0 >= M) return;

    int arow = row0 + m; if (arow >= M) arow = M - 1;
    short8 a;
#pragma unroll
    for (int j = 0; j < 8; ++j)
        a[j] = f2bs(ldf(X, arow * CIN + quad * 8 + j, bf));

    f32x4 acc[4] = {};
#pragma unroll
    for (int tt = 0; tt < 4; ++tt) {
        short8 bfr = *(const short8*)&WT[((lane & 15) + 16 * tt) * KP + quad * 8];
        acc[tt] = __builtin_amdgcn_mfma_f32_16x16x32_bf16(a, bfr, acc[tt], 0, 0, 0);
    }

    if (CIN == 34) {
        float x32[4], x33[4];
#pragma unroll
        for (int r = 0; r < 4; ++r) {
            int row = row0 + quad * 4 + r; if (row >= M) row = M - 1;
            x32[r] = ldf(X, row * CIN + 32, bf);
            x33[r] = ldf(X, row * CIN + 33, bf);
        }
#pragma unroll
        for (int tt = 0; tt < 4; ++tt) {
            int col = (lane & 15) + 16 * tt;
            float w32 = bs2f(WT[col * KP + 32]);
            float w33 = bs2f(WT[col * KP + 33]);
#pragma unroll
            for (int r = 0; r < 4; ++r)
                acc[tt][r] += x32[r] * w32 + x33[r] * w33;
        }
    }

    float vs[4] = {}, vd[4] = {}, ve[4] = {};
#pragma unroll
    for (int tt = 0; tt < 4; ++tt) {
        int col = (lane & 15) + 16 * tt;
        float bb = bl[col];
        float w0 = FV[col], w1 = FV[64 + col], w2 = FV[128 + col];
#pragma unroll
        for (int r = 0; r < 4; ++r) {
            int row = row0 + quad * 4 + r;
            float v = acc[tt][r] + bb;
            v = v > 0.f ? v : 0.01f * v;
            if (row < M) Y[(size_t)row * 64 + col] = __float2bfloat16(v);
            vs[r] += v * w0; vd[r] += v * w1; ve[r] += v * w2;
        }
    }
#pragma unroll
    for (int off = 1; off < 16; off <<= 1)
#pragma unroll
        for (int r = 0; r < 4; ++r) {
            vs[r] += __shfl_xor(vs[r], off);
            vd[r] += __shfl_xor(vd[r], off);
            ve[r] += __shfl_xor(ve[r], off);
        }
    int c = lane & 15;
    int row = row0 + quad * 4 + (c & 3);
    if (row < M && c < 12) {
        if (c < 4)       S0[row]  = sel4(vs, c & 3);
        else if (c < 8)  S1v[row] = sel4(vd, c & 3);
        else             S2v[row] = sel4(ve, c & 3);
    }
}

// ---- A: degree hist (global atomics) ∥ input projections + conv1 scores ---
__global__ __launch_bounds__(256) void k_hist_inproj(
    const int* __restrict__ bb_d, const int* __restrict__ pp_d,
    const int* __restrict__ bp_d, int* __restrict__ deg,
    const unsigned* __restrict__ probe_w,
    int E_bb, int E_pp, int E_bp, int NB, int NP, int nblk,
    const void* __restrict__ Xb, const void* __restrict__ Wb, const void* __restrict__ Bb,
    bf16* __restrict__ Yb, int MB,
    const void* __restrict__ Xp, const void* __restrict__ Wp, const void* __restrict__ Bp,
    bf16* __restrict__ Yp, int MP,
    const float* __restrict__ FVg,
    float* __restrict__ ss_bb, float* __restrict__ sd_bb, float* __restrict__ ss_bp,
    float* __restrict__ ss_pp, float* __restrict__ sd_pp, float* __restrict__ sd_bp)
{
    __shared__ short WT[64 * 40];
    __shared__ float bl[64];
    __shared__ float FV[192];
    __shared__ int cnt;
    if ((int)blockIdx.x < nblk) {
        int E_all = E_bb + E_pp + E_bp;
        int base = blockIdx.x * CHUNKE;
        int end = base + CHUNKE < E_all ? base + CHUNKE : E_all;
        for (int i = base + threadIdx.x; i < end; i += 256) {
            int d;
            if (i < E_bb) d = bb_d[i];
            else if (i < E_bb + E_pp) d = NB + pp_d[i - E_bb];
            else d = NB + NP + bp_d[i - E_bb - E_pp];
            atomicAdd(&deg[d], 1);
        }
    } else {
        int bfv = probe_bf(probe_w, &cnt);
        int bid = blockIdx.x - nblk;
        int nbb = (MB + 63) >> 6;
        if (bid < nbb)
            in_proj_body<32>(WT, bl, FV, bid, Xb, Wb, Bb, FVg,
                Yb, ss_bb, sd_bb, ss_bp, MB, bfv);
        else
            in_proj_body<34>(WT, bl, FV, bid - nbb, Xp, Wp, Bp, FVg + 192,
                Yp, ss_pp, sd_pp, sd_bp, MP, bfv);
    }
}

// ---- scans over deg -> ip_all (exclusive) ---------------------------------
__global__ __launch_bounds__(1024) void k_scan1(const int* __restrict__ deg,
                                                int* __restrict__ out,
                                                int* __restrict__ bsum, int n)
{
    __shared__ int wsum[16];
    int gid = blockIdx.x * 1024 + threadIdx.x;
    int lane = threadIdx.x & 63, wid = threadIdx.x >> 6;
    int v = (gid < n) ? deg[gid] : 0;
    int x = v;
#pragma unroll
    for (int off = 1; off < 64; off <<= 1) {
        int y = __shfl_up(x, off, 64);
        if (lane >= off) x += y;
    }
    if (lane == 63) wsum[wid] = x;
    __syncthreads();
    if (wid == 0 && lane < 16) {
        int w0 = wsum[lane];
#pragma unroll
        for (int off = 1; off < 16; off <<= 1) {
            int y = __shfl_up(w0, off, 16);
            if (lane >= off) w0 += y;
        }
        wsum[lane] = w0;
    }
    __syncthreads();
    int base = (wid > 0) ? wsum[wid - 1] : 0;
    int incl = base + x;
    if (gid < n) out[gid] = incl - v;
    if (threadIdx.x == 1023) bsum[blockIdx.x] = incl;
}

__global__ __launch_bounds__(1024) void k_scan2(int* __restrict__ bsum, int nb)
{
    __shared__ int wsum[16];
    int lane = threadIdx.x & 63, wid = threadIdx.x >> 6;
    int v = (threadIdx.x < nb) ? bsum[threadIdx.x] : 0;
    int x = v;
#pragma unroll
    for (int off = 1; off < 64; off <<= 1) {
        int y = __shfl_up(x, off, 64);
        if (lane >= off) x += y;
    }
    if (lane == 63) wsum[wid] = x;
    __syncthreads();
    if (wid == 0 && lane < 16) {
        int w0 = wsum[lane];
#pragma unroll
        for (int off = 1; off < 16; off <<= 1) {
            int y = __shfl_up(w0, off, 16);
            if (lane >= off) w0 += y;
        }
        wsum[lane] = w0;
    }
    __syncthreads();
    int base = (wid > 0) ? wsum[wid - 1] : 0;
    if (threadIdx.x < nb) bsum[threadIdx.x] = base + x - v;
}

__global__ __launch_bounds__(1024) void k_scan3(int* __restrict__ indptr,
                                                int* __restrict__ cur,
                                                const int* __restrict__ bsum,
                                                int n, int E)
{
    int gid = blockIdx.x * 1024 + threadIdx.x;
    if (gid < n) {
        int v = indptr[gid] + bsum[blockIdx.x];
        indptr[gid] = v;
        cur[gid] = v;
    }
    if (gid == 0) indptr[n] = E;
}

// ---- E: direct scatter to final CSR position, score+exp fused -------------
__global__ __launch_bounds__(256) void k_scatter2(
    const int* __restrict__ bb_s, const int* __restrict__ bb_d,
    const int* __restrict__ pp_s, const int* __restrict__ pp_d,
    const int* __restrict__ bp_s, const int* __restrict__ bp_d,
    const float* __restrict__ ss_bb, const float* __restrict__ sd_bb,
    const float* __restrict__ ss_pp, const float* __restrict__ sd_pp,
    const float* __restrict__ ss_bp, const float* __restrict__ sd_bp,
    int* __restrict__ cur, int2* __restrict__ sw,
    int E_bb, int E_pp, int E_bp, int NB, int NP)
{
    int E_all = E_bb + E_pp + E_bp;
    int base = blockIdx.x * CHUNKE;
    int end = base + CHUNKE < E_all ? base + CHUNKE : E_all;
    for (int i = base + threadIdx.x; i < end; i += 256) {
        int s, dg; float ssv, sdv;
        if (i < E_bb) {
            s = bb_s[i]; int d = bb_d[i]; dg = d;
            ssv = ss_bb[s]; sdv = sd_bb[d];
        } else if (i < E_bb + E_pp) {
            int j = i - E_bb; s = pp_s[j]; int d = pp_d[j]; dg = NB + d;
            ssv = ss_pp[s]; sdv = sd_pp[d];
        } else {
            int j = i - E_bb - E_pp; s = bp_s[j]; int d = bp_d[j]; dg = NB + NP + d;
            ssv = ss_bp[s]; sdv = sd_bp[d];
        }
        int p = atomicAdd(&cur[dg], 1);
        int2 pk; pk.x = s; pk.y = __float_as_int(__expf(lrelu2(ssv + sdv)));
        sw[p] = pk;
    }
}

// ---- conv1 gather bodies: raw tables, write normalized aggregates ---------
static __device__ __forceinline__ void gather1_body(
    int bid, const int* __restrict__ ip, const int2* __restrict__ sw,
    const float* __restrict__ SS, const float* __restrict__ SD,
    const bf16* __restrict__ HS, bf16* __restrict__ OUT, int M)
{
    int lane = threadIdx.x & 63;
    int half = lane >> 5, hl = lane & 31;
    int d = bid * 4 + (threadIdx.x >> 6);
    if (d >= M) return;
    const u32* H32 = (const u32*)HS;
    float ax = 0.f, ay = 0.f, den = 0.f;
    if (half == 0) {
        float ex = __expf(lrelu2(SS[d] + SD[d]));
        u32 h = H32[(size_t)d * 32 + hl];
        ax = lo16(h) * ex; ay = hi16(h) * ex; den = ex;
    }
    int j1 = ip[d + 1];
    int j = ip[d] + half;
    for (; j + 6 < j1; j += 8) {
        int2 p0 = sw[j], p1 = sw[j + 2], p2 = sw[j + 4], p3 = sw[j + 6];
        u32 h0 = H32[(size_t)p0.x * 32 + hl];
        u32 h1 = H32[(size_t)p1.x * 32 + hl];
        u32 h2 = H32[(size_t)p2.x * 32 + hl];
        u32 h3 = H32[(size_t)p3.x * 32 + hl];
        float e0 = __int_as_float(p0.y), e1 = __int_as_float(p1.y);
        float e2 = __int_as_float(p2.y), e3 = __int_as_float(p3.y);
        ax += lo16(h0) * e0 + lo16(h1) * e1 + lo16(h2) * e2 + lo16(h3) * e3;
        ay += hi16(h0) * e0 + hi16(h1) * e1 + hi16(h2) * e2 + hi16(h3) * e3;
        den += (e0 + e1) + (e2 + e3);
    }
    for (; j < j1; j += 2) {
        int2 p0 = sw[j];
        u32 h0 = H32[(size_t)p0.x * 32 + hl];
        float e0 = __int_as_float(p0.y);
        ax += lo16(h0) * e0; ay += hi16(h0) * e0; den += e0;
    }
    ax += __shfl_xor(ax, 32); ay += __shfl_xor(ay, 32); den += __shfl_xor(den, 32);
    if (half == 0) {
        float inv = 1.f / den;   // self loop -> den > 0
        ((u32*)OUT)[(size_t)d * 32 + hl] = pack2(ax * inv, ay * inv);
    }
}

static __device__ __forceinline__ void gather2_body(
    int bid, const int* __restrict__ ip1, const int2* __restrict__ sw,
    const float* __restrict__ SS1, const float* __restrict__ SD1,
    const bf16* __restrict__ H1T,
    const int* __restrict__ ip2, const bf16* __restrict__ H2T,
    bf16* __restrict__ O1, bf16* __restrict__ O2, int M)
{
    int lane = threadIdx.x & 63;
    int half = lane >> 5, hl = lane & 31;
    int d = bid * 4 + (threadIdx.x >> 6);
    if (d >= M) return;
    const u32* H1 = (const u32*)H1T;
    const u32* H2 = (const u32*)H2T;
    float a1x = 0.f, a1y = 0.f, den1 = 0.f;
    if (half == 0) {
        float ex = __expf(lrelu2(SS1[d] + SD1[d]));
        u32 h = H1[(size_t)d * 32 + hl];
        a1x = lo16(h) * ex; a1y = hi16(h) * ex; den1 = ex;
    }
    int j1 = ip1[d + 1];
    int j = ip1[d] + half;
    for (; j + 6 < j1; j += 8) {
        int2 p0 = sw[j], p1 = sw[j + 2], p2 = sw[j + 4], p3 = sw[j + 6];
        u32 h0 = H1[(size_t)p0.x * 32 + hl];
        u32 h1 = H1[(size_t)p1.x * 32 + hl];
        u32 h2 = H1[(size_t)p2.x * 32 + hl];
        u32 h3 = H1[(size_t)p3.x * 32 + hl];
        float e0 = __int_as_float(p0.y), e1 = __int_as_float(p1.y);
        float e2 = __int_as_float(p2.y), e3 = __int_as_float(p3.y);
        a1x += lo16(h0) * e0 + lo16(h1) * e1 + lo16(h2) * e2 + lo16(h3) * e3;
        a1y += hi16(h0) * e0 + hi16(h1) * e1 + hi16(h2) * e2 + hi16(h3) * e3;
        den1 += (e0 + e1) + (e2 + e3);
    }
    for (; j < j1; j += 2) {
        int2 p0 = sw[j];
        u32 h0 = H1[(size_t)p0.x * 32 + hl];
        float e0 = __int_as_float(p0.y);
        a1x += lo16(h0) * e0; a1y += hi16(h0) * e0; den1 += e0;
    }
    float a2x = 0.f, a2y = 0.f, den2 = 0.f;
    j1 = ip2[d + 1];
    j = ip2[d] + half;
    for (; j + 6 < j1; j += 8) {
        int2 p0 = sw[j], p1 = sw[j + 2], p2 = sw[j + 4], p3 = sw[j + 6];
        u32 h0 = H2[(size_t)p0.x * 32 + hl];
        u32 h1 = H2[(size_t)p1.x * 32 + hl];
        u32 h2 = H2[(size_t)p2.x * 32 + hl];
        u32 h3 = H2[(size_t)p3.x * 32 + hl];
        float e0 = __int_as_float(p0.y), e1 = __int_as_float(p1.y);
        float e2 = __int_as_float(p2.y), e3 = __int_as_float(p3.y);
        a2x += lo16(h0) * e0 + lo16(h1) * e1 + lo16(h2) * e2 + lo16(h3) * e3;
        a2y += hi16(h0) * e0 + hi16(h1) * e1 + hi16(h2) * e2 + hi16(h3) * e3;
        den2 += (e0 + e1) + (e2 + e3);
    }
    for (; j < j1; j += 2) {
        int2 p0 = sw[j];
        u32 h0 = H2[(size_t)p0.x * 32 + hl];
        float e0 = __int_as_float(p0.y);
        a2x += lo16(h0) * e0; a2y += hi16(h0) * e0; den2 += e0;
    }
    a1x += __shfl_xor(a1x, 32); a1y += __shfl_xor(a1y, 32); den1 += __shfl_xor(den1, 32);
    a2x += __shfl_xor(a2x, 32); a2y += __shfl_xor(a2y, 32); den2 += __shfl_xor(den2, 32);
    if (half == 0) {
        float inv1 = 1.f / den1;                       // self loop -> den1 > 0
        float inv2 = den2 > 0.f ? 1.f / den2 : 0.f;
        ((u32*)O1)[(size_t)d * 32 + hl] = pack2(a1x * inv1, a1y * inv1);
        ((u32*)O2)[(size_t)d * 32 + hl] = pack2(a2x * inv2, a2y * inv2);
    }
}

// merged conv1 gathers (raw hb/hp tables)
__global__ __launch_bounds__(256) void k_gather12(
    const int* __restrict__ ip_bb, const int2* __restrict__ sw,
    const float* __restrict__ ss_bb, const float* __restrict__ sd_bb,
    const bf16* __restrict__ hb, bf16* __restrict__ agg_bb, int NB,
    const int* __restrict__ ip_pp, const int* __restrict__ ip_bp,
    const float* __restrict__ ss_pp, const float* __restrict__ sd_pp,
    const bf16* __restrict__ hp,
    bf16* __restrict__ agg_pp, bf16* __restrict__ agg_bp, int NP)
{
    int nbb = (NB + 3) >> 2;
    if ((int)blockIdx.x < nbb)
        gather1_body(blockIdx.x, ip_bb, sw, ss_bb, sd_bb, hb, agg_bb, NB);
    else
        gather2_body(blockIdx.x - nbb, ip_pp, sw, ss_pp, sd_pp, hp,
                     ip_bp, hb, agg_pp, agg_bp, NP);
}

// ---- H: fused conv1-postproj (stage1) + conv2-proj (stage2) ---------------
// stage1: rows = lrelu(A1@W1a [+ A2@W1b] + bias) -> LDS (bf16, 64x64)
// stage2: hs2 = rows@W2a [, rows@W2b for dst scores]; scores via a-vectors.
template <bool D1, bool D2>
static __device__ __forceinline__ void fused_body(
    short* WT1, short* WT2, short* HT, float* bl, int bid,
    const bf16* __restrict__ A1, const bf16* __restrict__ A2,
    const void* W1a, const void* W1b, const void* B1a, const void* B1b,
    const void* W2a, const void* W2b,
    const void* av0, const void* av1, const void* av2,
    bf16* __restrict__ HS,
    float* __restrict__ S0, float* __restrict__ S1v, float* __restrict__ S2v,
    int M, int bf)
{
    constexpr int KP = 72;
    for (int i = threadIdx.x; i < 64 * 64; i += 256) {
        int n = i >> 6, k = i & 63;
        WT1[n * KP + k] = f2bs(ldf(W1a, k * 64 + n, bf));
        if (D1) WT1[(64 + n) * KP + k] = f2bs(ldf(W1b, k * 64 + n, bf));
    }
    for (int i = threadIdx.x; i < 32 * 64; i += 256) {
        int n = i >> 6, k = i & 63;      // n < 32
        WT2[n * KP + k] = f2bs(ldf(W2a, k * 32 + n, bf));
        if (D2) WT2[(32 + n) * KP + k] = f2bs(ldf(W2b, k * 32 + n, bf));
    }
    if (threadIdx.x < 64) {
        float b = ldf(B1a, threadIdx.x, bf);
        if (D1) b += ldf(B1b, threadIdx.x, bf);
        bl[threadIdx.x] = b;
    }
    __syncthreads();

    int lane = threadIdx.x & 63;
    int wv   = threadIdx.x >> 6;
    int m = lane & 15, quad = lane >> 4;
    int row0 = (bid * 4 + wv) * 16;
    bool act = row0 < M;

    const short* A1s = (const short*)A1;
    const short* A2s = (const short*)A2;
    if (act) {
        int arow = row0 + m; if (arow >= M) arow = M - 1;
        f32x4 acc[4] = {};
#pragma unroll
        for (int ks = 0; ks < 2; ++ks) {
            short8 a1 = *(const short8*)&A1s[(size_t)arow * 64 + ks * 32 + quad * 8];
#pragma unroll
            for (int tt = 0; tt < 4; ++tt) {
                short8 bfr = *(const short8*)&WT1[((lane & 15) + 16 * tt) * KP + ks * 32 + quad * 8];
                acc[tt] = __builtin_amdgcn_mfma_f32_16x16x32_bf16(a1, bfr, acc[tt], 0, 0, 0);
            }
            if (D1) {
                short8 a2 = *(const short8*)&A2s[(size_t)arow * 64 + ks * 32 + quad * 8];
#pragma unroll
                for (int tt = 0; tt < 4; ++tt) {
                    short8 bfr = *(const short8*)&WT1[(64 + (lane & 15) + 16 * tt) * KP + ks * 32 + quad * 8];
                    acc[tt] = __builtin_amdgcn_mfma_f32_16x16x32_bf16(a2, bfr, acc[tt], 0, 0, 0);
                }
            }
        }
#pragma unroll
        for (int tt = 0; tt < 4; ++tt) {
            int col = (lane & 15) + 16 * tt;
            float bb = bl[col];
#pragma unroll
            for (int r = 0; r < 4; ++r) {
                float v = acc[tt][r] + bb;
                v = v > 0.f ? v : 0.01f * v;
                HT[(wv * 16 + quad * 4 + r) * 80 + col] = f2bs(v);
            }
        }
    }
    __syncthreads();

    f32x4 acc2[D2 ? 4 : 2] = {};
    if (act) {
        int arow = row0 + m; if (arow >= M) arow = M - 1;
        int al = arow - bid * 64;        // in [0,64)
#pragma unroll
        for (int ks = 0; ks < 2; ++ks) {
            short8 a = *(const short8*)&HT[al * 80 + ks * 32 + quad * 8];
#pragma unroll
            for (int tt = 0; tt < (D2 ? 4 : 2); ++tt) {
                short8 bfr = *(const short8*)&WT2[((lane & 15) + 16 * tt) * KP + ks * 32 + quad * 8];
                acc2[tt] = __builtin_amdgcn_mfma_f32_16x16x32_bf16(a, bfr, acc2[tt], 0, 0, 0);
            }
        }
    }

    float vs[4] = {}, vd[4] = {}, ve[4] = {};
#pragma unroll
    for (int tt = 0; tt < 2; ++tt) {
        int col = (lane & 15) + 16 * tt;
        float a0 = ldf(av0, col, bf);
#pragma unroll
        for (int r = 0; r < 4; ++r) vs[r] += acc2[tt][r] * a0;
        if (D1) {
            float a1 = ldf(av1, col, bf);
#pragma unroll
            for (int r = 0; r < 4; ++r) vd[r] += acc2[tt][r] * a1;
        }
    }
    if (D2) {
#pragma unroll
        for (int tt = 0; tt < 2; ++tt) {
            int col = (lane & 15) + 16 * tt;
            float a2 = ldf(av2, col, bf);
#pragma unroll
            for (int r = 0; r < 4; ++r) ve[r] += acc2[2 + tt][r] * a2;
        }
    }
#pragma unroll
    for (int off = 1; off < 16; off <<= 1)
#pragma unroll
        for (int r = 0; r < 4; ++r) {
            vs[r] += __shfl_xor(vs[r], off);
            if (D1) vd[r] += __shfl_xor(vd[r], off);
            if (D2) ve[r] += __shfl_xor(ve[r], off);
        }
    int c = lane & 15;
    int row = row0 + quad * 4 + (c & 3);
    if (act && row < M) {
        if (c < 4)                    S0[row]  = sel4(vs, c & 3);
        else if (D1 && c < 8)         S1v[row] = sel4(vd, c & 3);
        else if (D2 && c >= 8 && c < 12) S2v[row] = sel4(ve, c & 3);
    }
    if (act) {
#pragma unroll
        for (int tt = 0; tt < 2; ++tt) {
            int col = (lane & 15) + 16 * tt;
#pragma unroll
            for (int r = 0; r < 4; ++r) {
                int row2 = row0 + quad * 4 + r;
                if (row2 < M)
                    HS[(size_t)row2 * 32 + col] = __float2bfloat16(acc2[tt][r]);
            }
        }
    }
}

__global__ __launch_bounds__(256) void k_fused_proj(
    const bf16* __restrict__ agg_pp, const bf16* __restrict__ agg_bp,
    const void* W_pp1, const void* Ws_bp1, const void* b_pp1, const void* b_bp1,
    const void* W_pp2, const void* Wd_bp2,
    const void* as_pp2, const void* ad_pp2, const void* ad_bp2,
    bf16* __restrict__ hs2_pp, float* __restrict__ ss2_pp,
    float* __restrict__ sd2_pp, float* __restrict__ sd2_bp, int MP,
    const bf16* __restrict__ agg_bb, const void* W_bb1, const void* b_bb1,
    const void* Ws_bp2, const void* as_bp2,
    bf16* __restrict__ hs2_bp, float* __restrict__ ss2_bp, int MB,
    const int* __restrict__ flag)
{
    const int bf = *flag;
    __shared__ __align__(16) short WT1[128 * 72];
    __shared__ __align__(16) short WT2[64 * 72];
    __shared__ __align__(16) short HT[64 * 80];
    __shared__ float bl[64];
    int npb = (MP + 63) >> 6;
    if ((int)blockIdx.x < npb)
        fused_body<true, true>(WT1, WT2, HT, bl, blockIdx.x,
            agg_pp, agg_bp, W_pp1, Ws_bp1, b_pp1, b_bp1,
            W_pp2, Wd_bp2, as_pp2, ad_pp2, ad_bp2,
            hs2_pp, ss2_pp, sd2_pp, sd2_bp, MP, bf);
    else
        fused_body<false, false>(WT1, WT2, HT, bl, blockIdx.x - npb,
            agg_bb, nullptr, W_bb1, nullptr, b_bb1, nullptr,
            Ws_bp2, nullptr, as_bp2, nullptr, nullptr,
            hs2_bp, ss2_bp, nullptr, nullptr, MB, bf);
}

// ---- conv2 gather (C=32) + output head, 2 edges/quad unroll ---------------
__global__ __launch_bounds__(256) void k_gather_out(
    const int* __restrict__ ip1, const int2* __restrict__ sw,
    const float* __restrict__ SS1, const float* __restrict__ SD1,
    const bf16* __restrict__ HS1,
    const int* __restrict__ ip2,
    const float* __restrict__ SS2, const float* __restrict__ SD2,
    const bf16* __restrict__ HS2,
    const void* __restrict__ b1, const void* __restrict__ b2,
    const void* __restrict__ Wout, const void* __restrict__ bout,
    void* __restrict__ OUT, int M, const int* __restrict__ flag)
{
    const int bf = *flag;
    int lane = threadIdx.x & 63;
    int q = lane >> 4, hl = lane & 15;
    int d = blockIdx.x * 4 + (threadIdx.x >> 6);
    if (d >= M) return;
    const u32* H1 = (const u32*)HS1;
    const u32* H2 = (const u32*)HS2;
    float sdd = SD1[d];
    float a1x = 0.f, a1y = 0.f, den1 = 0.f;
    if (q == 0) {
        float ex = __expf(lrelu2(SS1[d] + sdd));
        u32 h = H1[(size_t)d * 16 + hl];
        a1x = lo16(h) * ex; a1y = hi16(h) * ex; den1 = ex;
    }
    int j1 = ip1[d + 1];
    int j = ip1[d] + q;
    for (; j + 4 < j1; j += 8) {
        int s0 = sw[j].x, s1 = sw[j + 4].x;
        u32 h0 = H1[(size_t)s0 * 16 + hl];
        u32 h1 = H1[(size_t)s1 * 16 + hl];
        float e0 = __expf(lrelu2(SS1[s0] + sdd));
        float e1 = __expf(lrelu2(SS1[s1] + sdd));
        a1x += lo16(h0) * e0 + lo16(h1) * e1;
        a1y += hi16(h0) * e0 + hi16(h1) * e1;
        den1 += e0 + e1;
    }
    if (j < j1) {
        int s0 = sw[j].x;
        u32 h0 = H1[(size_t)s0 * 16 + hl];
        float e0 = __expf(lrelu2(SS1[s0] + sdd));
        a1x += lo16(h0) * e0; a1y += hi16(h0) * e0; den1 += e0;
    }
    float sdd2 = SD2[d];
    float a2x = 0.f, a2y = 0.f, den2 = 0.f;
    j1 = ip2[d + 1];
    j = ip2[d] + q;
    for (; j + 4 < j1; j += 8) {
        int s0 = sw[j].x, s1 = sw[j + 4].x;
        u32 h0 = H2[(size_t)s0 * 16 + hl];
        u32 h1 = H2[(size_t)s1 * 16 + hl];
        float e0 = __expf(lrelu2(SS2[s0] + sdd2));
        float e1 = __expf(lrelu2(SS2[s1] + sdd2));
        a2x += lo16(h0) * e0 + lo16(h1) * e1;
        a2y += hi16(h0) * e0 + hi16(h1) * e1;
        den2 += e0 + e1;
    }
    if (j < j1) {
        int s0 = sw[j].x;
        u32 h0 = H2[(size_t)s0 * 16 + hl];
        float e0 = __expf(lrelu2(SS2[s0] + sdd2));
        a2x += lo16(h0) * e0; a2y += hi16(h0) * e0; den2 += e0;
    }
    a1x += __shfl_xor(a1x, 16); a1y += __shfl_xor(a1y, 16); den1 += __shfl_xor(den1, 16);
    a2x += __shfl_xor(a2x, 16); a2y += __shfl_xor(a2y, 16); den2 += __shfl_xor(den2, 16);
    a1x += __shfl_xor(a1x, 32); a1y += __shfl_xor(a1y, 32); den1 += __shfl_xor(den1, 32);
    a2x += __shfl_xor(a2x, 32); a2y += __shfl_xor(a2y, 32); den2 += __shfl_xor(den2, 32);
    float inv2 = den2 > 0.f ? 1.f / den2 : 0.f;
    float vx = a1x / den1 + a2x * inv2 + ldf(b1, 2 * hl, bf) + ldf(b2, 2 * hl, bf);
    float vy = a1y / den1 + a2y * inv2 + ldf(b1, 2 * hl + 1, bf) + ldf(b2, 2 * hl + 1, bf);
    vx = vx > 0.f ? vx : 0.01f * vx;
    vy = vy > 0.f ? vy : 0.01f * vy;
    float t = vx * ldf(Wout, 2 * hl, bf) + vy * ldf(Wout, 2 * hl + 1, bf);
#pragma unroll
    for (int off = 1; off < 16; off <<= 1) t += __shfl_xor(t, off);
    if (lane == 0) {
        float r = t + ldf(bout, 0, bf);
        if (bf) ((bf16*)OUT)[d] = __float2bfloat16(r);
        else    ((float*)OUT)[d] = r;
    }
}

// ---------------------------------------------------------------------------
extern "C" void kernel_launch(void* const* d_in, const int* in_sizes, int n_in,
                              void* d_out, int out_size, void* d_ws, size_t ws_size,
                              hipStream_t stream)
{
    const void* x_b = d_in[0];
    const void* x_p = d_in[1];
    const int* ei_bb = (const int*)d_in[2];
    const int* ei_pp = (const int*)d_in[3];
    const int* bp_s  = (const int*)d_in[4];
    const int* bp_d  = (const int*)d_in[5];
    const void *W_in_b = d_in[6],  *b_in_b = d_in[7];
    const void *W_in_p = d_in[8],  *b_in_p = d_in[9];
    const void *W_bb1 = d_in[10], *as_bb1 = d_in[11], *ad_bb1 = d_in[12], *b_bb1 = d_in[13];
    const void *W_pp1 = d_in[14], *as_pp1 = d_in[15], *ad_pp1 = d_in[16], *b_pp1 = d_in[17];
    const void *Ws_bp1 = d_in[18], *Wd_bp1 = d_in[19], *as_bp1 = d_in[20], *ad_bp1 = d_in[21], *b_bp1 = d_in[22];
    // d_in[23..26] = conv2 b->b params: dead code in reference
    const void *W_pp2 = d_in[27], *as_pp2 = d_in[28], *ad_pp2 = d_in[29], *b_pp2 = d_in[30];
    const void *Ws_bp2 = d_in[31], *Wd_bp2 = d_in[32], *as_bp2 = d_in[33], *ad_bp2 = d_in[34], *b_bp2 = d_in[35];
    const void *W_out = d_in[36], *b_out = d_in[37];

    const int NB   = in_sizes[0] / 32;
    const int NP   = in_sizes[1] / 34;
    const int E_bb = in_sizes[2] / 2;
    const int E_pp = in_sizes[3] / 2;
    const int E_bp = in_sizes[4];
    const int E_all = E_bb + E_pp + E_bp;
    const int NALL  = NB + 2 * NP;
    const int* bb_s = ei_bb;  const int* bb_d = ei_bb + E_bb;
    const int* pp_s = ei_pp;  const int* pp_d = ei_pp + E_pp;
    (void)ws_size; (void)n_in; (void)out_size;

    const int nblk  = (E_all + CHUNKE - 1) / CHUNKE;

    char* base = (char*)d_ws;
    size_t o = 0;
    auto alloc = [&](size_t bytes) { char* p = base + o; o += (bytes + 255) & ~(size_t)255; return p; };

    // --- small persistent ---
    int* flag  = (int*)alloc(256);
    float* FVg = (float*)alloc(6 * 64 * 4);
    int* bsum  = (int*)alloc(1024 * 4);
    int* deg   = (int*)alloc((size_t)NALL * 4);
    int* cur   = (int*)alloc((size_t)NALL * 4);
    int* ip_all = (int*)alloc((size_t)(NALL + 1) * 4);
    int2* sw = (int2*)alloc((size_t)E_all * 8);
    float* ss_bb = (float*)alloc((size_t)NB * 4);
    float* sd_bb = (float*)alloc((size_t)NB * 4);
    float* ss_bp = (float*)alloc((size_t)NB * 4);
    float* ss_pp = (float*)alloc((size_t)NP * 4);
    float* sd_pp = (float*)alloc((size_t)NP * 4);
    float* sd_bp = (float*)alloc((size_t)NP * 4);
    float* ss2_bp = ss_bb;   // conv1 scores dead after k_scatter2
    float* ss2_pp = ss_pp;
    float* sd2_pp = sd_pp;
    float* sd2_bp = sd_bp;

    // --- feature slots ---
    char* S1 = alloc((size_t)NB * 64 * 2);   // hb -> hs2_bp
    char* S2 = alloc((size_t)NP * 64 * 2);   // hp -> hs2_pp
    char* S3 = alloc((size_t)NB * 64 * 2);   // agg_bb
    char* S5 = alloc((size_t)NP * 64 * 2);   // agg_bp
    char* S6 = alloc((size_t)NP * 64 * 2);   // agg_pp

    bf16* hb     = (bf16*)S1;
    bf16* hp     = (bf16*)S2;
    bf16* agg_bb = (bf16*)S3;
    bf16* agg_bp = (bf16*)S5;
    bf16* agg_pp = (bf16*)S6;
    bf16* hs2_pp = (bf16*)S2;   // overwrites hp (dead after gather12)
    bf16* hs2_bp = (bf16*)S1;   // overwrites hb (dead after gather12)

    auto cdiv = [](int a, int b) { return (a + b - 1) / b; };

    const int* ip_bb = ip_all;
    const int* ip_pp = ip_all + NB;
    const int* ip_bp = ip_all + NB + NP;

    // A0. folded conv1 score vectors (block 0) + zero deg[] (blocks 1..)
    k_fv<<<1 + 64, 256, 0, stream>>>(
        (const unsigned*)x_b, flag,
        W_bb1, as_bb1, ad_bb1, Ws_bp1, as_bp1,
        W_pp1, as_pp1, ad_pp1, Wd_bp1, ad_bp1, FVg, deg, NALL);

    // A. degree hist (global atomics) ∥ input projections + conv1 scores
    k_hist_inproj<<<nblk + cdiv(NB, 64) + cdiv(NP, 64), 256, 0, stream>>>(
        bb_d, pp_d, bp_d, deg, (const unsigned*)x_b,
        E_bb, E_pp, E_bp, NB, NP, nblk,
        x_b, W_in_b, b_in_b, hb, NB, x_p, W_in_p, b_in_p, hp, NP,
        FVg, ss_bb, sd_bb, ss_bp, ss_pp, sd_pp, sd_bp);

    // B-D. scan deg -> ip_all (exclusive), cur = copy
    int sb1 = cdiv(NALL, 1024);
    k_scan1<<<sb1, 1024, 0, stream>>>(deg, ip_all, bsum, NALL);
    k_scan2<<<1, 1024, 0, stream>>>(bsum, sb1);
    k_scan3<<<sb1, 1024, 0, stream>>>(ip_all, cur, bsum, NALL, E_all);

    // E. direct scatter to final CSR positions, score+exp fused
    k_scatter2<<<nblk, 256, 0, stream>>>(
        bb_s, bb_d, pp_s, pp_d, bp_s, bp_d,
        ss_bb, sd_bb, ss_pp, sd_pp, ss_bp, sd_bp,
        cur, sw, E_bb, E_pp, E_bp, NB, NP);

    // G. conv1 gathers over RAW hb/hp (shared table for bb+bp edges)
    k_gather12<<<cdiv(NB, 4) + cdiv(NP, 4), 256, 0, stream>>>(
        ip_bb, sw, ss_bb, sd_bb, hb, agg_bb, NB,
        ip_pp, ip_bp, ss_pp, sd_pp, hp, agg_pp, agg_bp, NP);

    // H. fused conv1-postproj + conv2 projections + conv2 scores
    k_fused_proj<<<cdiv(NP, 64) + cdiv(NB, 64), 256, 0, stream>>>(
        agg_pp, agg_bp, W_pp1, Ws_bp1, b_pp1, b_bp1,
        W_pp2, Wd_bp2, as_pp2, ad_pp2, ad_bp2,
        hs2_pp, ss2_pp, sd2_pp, sd2_bp, NP,
        agg_bb, W_bb1, b_bb1, Ws_bp2, as_bp2,
        hs2_bp, ss2_bp, NB, flag);

    // I. conv2 gather + output head
    k_gather_out<<<cdiv(NP, 4), 256, 0, stream>>>(
        ip_pp, sw, ss2_pp, sd2_pp, hs2_pp,
        ip_bp, ss2_bp, sd2_bp, hs2_bp,
        b_pp2, b_bp2, W_out, b_out, d_out, NP, flag);
}

// Round 4
// 405.423 us; speedup vs baseline: 1.2623x; 1.2623x over previous
//
#include <hip/hip_runtime.h>
#include <hip/hip_bf16.h>
#include <cstdint>
#include <cstddef>

// ---------------------------------------------------------------------------
// HeteroGNN (2-layer hetero GAT) on MI355X, gfx950.  Round 15.
//  - r14 post-mortem: direct-atomic scatter wrote 8B at random positions ->
//    102MB write-allocate traffic (vs 13.6MB payload).  REVERTED to the
//    bucketed scatter+finalize (line-clustered writes, proven in r11/r13).
//  - Serial-overhead removal vs r13 (which lost 30us to structure):
//      * k_fv merged into hist kernel (block 0 = FV+flag, rest = hist)
//      * input projection now overlaps the SCATTER (not the cheap hist):
//        hist alone ~9us; scatter hides under ~38us of projection work
//      * r14's k_fused_proj kept: conv1-postproj + conv2-proj + scores in
//        ONE kernel (replaces separate postproj+proj2, -38MB traffic)
//  - Kept: commuted conv1 (raw-table gather -> aggregates -> postproj),
//    packed int2 edge payload, conv2 in projected 32-dim space.
// ---------------------------------------------------------------------------

typedef __attribute__((ext_vector_type(8))) short short8;   // 8 bf16 (4 VGPR)
typedef __attribute__((ext_vector_type(4))) float f32x4;    // MFMA acc
typedef unsigned int u32;
typedef __hip_bfloat16 bf16;

#define ABITS 9             // bucket = concat_dst >> ABITS  (512 dsts/bucket)
#define CHUNKE 8192         // edges per block in bucket passes

static __device__ __forceinline__ float ldf(const void* p, int i, int bf) {
    return bf ? __bfloat162float(((const bf16*)p)[i]) : ((const float*)p)[i];
}

static __device__ __forceinline__ short f2bs(float f) {
    bf16 h = __float2bfloat16(f);
    return *reinterpret_cast<short*>(&h);
}
static __device__ __forceinline__ float bs2f(short s) {
    bf16 h = *reinterpret_cast<bf16*>(&s);
    return __bfloat162float(h);
}
static __device__ __forceinline__ float lo16(u32 u) { return bs2f((short)(u & 0xffffu)); }
static __device__ __forceinline__ float hi16(u32 u) { return bs2f((short)(u >> 16)); }
static __device__ __forceinline__ u32 pack2(float x, float y) {
    return (u32)(unsigned short)f2bs(x) | ((u32)(unsigned short)f2bs(y) << 16);
}
static __device__ __forceinline__ float sel4(const float* a, int i) {
    return i == 0 ? a[0] : i == 1 ? a[1] : i == 2 ? a[2] : a[3];
}
static __device__ __forceinline__ float lrelu2(float x) { return x > 0.f ? x : 0.2f * x; }

// per-block inline dtype probe (4 KB of x_b, L2-hot after first block)
static __device__ __forceinline__ int probe_bf(const unsigned* __restrict__ w, int* cnt) {
    if (threadIdx.x == 0) *cnt = 0;
    __syncthreads();
    int c = 0;
#pragma unroll
    for (int j = 0; j < 4; ++j) {
        unsigned u = w[threadIdx.x * 4 + j];
        unsigned e = (u >> 7) & 0xffu;
        c += (e >= 100u && e <= 145u) ? 1 : 0;
    }
    atomicAdd(cnt, c);
    __syncthreads();
    int r = (*cnt > 614) ? 1 : 0;
    __syncthreads();
    return r;
}

// ---- A: block 0 = FV vectors + dtype flag; blocks 1.. = bucket hist -------
__global__ __launch_bounds__(256) void k_fv_hist(
    const unsigned* __restrict__ probe_w, int* __restrict__ flag,
    const void* W_bb1, const void* as_bb1, const void* ad_bb1,
    const void* Ws_bp1, const void* as_bp1,
    const void* W_pp1, const void* as_pp1, const void* ad_pp1,
    const void* Wd_bp1, const void* ad_bp1,
    float* __restrict__ FVg,
    const int* __restrict__ bb_d, const int* __restrict__ pp_d,
    const int* __restrict__ bp_d, int* __restrict__ histM,
    int E_bb, int E_pp, int E_bp, int NB, int NP, int nbkt, int nblk)
{
    __shared__ int aux[1 << ABITS];
    if (blockIdx.x == 0) {
        int bf = probe_bf(probe_w, &aux[0]);
        if (threadIdx.x == 0) *flag = bf;
        int lane = threadIdx.x & 63, wv = threadIdx.x >> 6;
        const void* Ws[6] = { W_bb1, W_bb1, Ws_bp1, W_pp1, W_pp1, Wd_bp1 };
        const void* av[6] = { as_bb1, ad_bb1, as_bp1, as_pp1, ad_pp1, ad_bp1 };
#pragma unroll
        for (int v = 0; v < 6; ++v) {
            float a = ldf(av[v], lane, bf);
            for (int k = wv; k < 64; k += 4) {
                float p = ldf(Ws[v], k * 64 + lane, bf) * a;   // coalesced row read
#pragma unroll
                for (int off = 1; off < 64; off <<= 1) p += __shfl_xor(p, off);
                if (lane == 0) FVg[v * 64 + k] = p;
            }
        }
        return;
    }
    int blk = blockIdx.x - 1;
    for (int i = threadIdx.x; i < nbkt; i += 256) aux[i] = 0;
    __syncthreads();
    int E_all = E_bb + E_pp + E_bp;
    int base = blk * CHUNKE;
    int end = base + CHUNKE < E_all ? base + CHUNKE : E_all;
    for (int i = base + threadIdx.x; i < end; i += 256) {
        int d;
        if (i < E_bb) d = bb_d[i];
        else if (i < E_bb + E_pp) d = NB + pp_d[i - E_bb];
        else d = NB + NP + bp_d[i - E_bb - E_pp];
        atomicAdd(&aux[d >> ABITS], 1);
    }
    __syncthreads();
    for (int i = threadIdx.x; i < nbkt; i += 256)
        histM[(size_t)i * nblk + blk] = aux[i];
}

// ---- scans over histM -> histS --------------------------------------------
__global__ __launch_bounds__(1024) void k_scan1(const int* __restrict__ deg,
                                                int* __restrict__ out,
                                                int* __restrict__ bsum, int n)
{
    __shared__ int wsum[16];
    int gid = blockIdx.x * 1024 + threadIdx.x;
    int lane = threadIdx.x & 63, wid = threadIdx.x >> 6;
    int v = (gid < n) ? deg[gid] : 0;
    int x = v;
#pragma unroll
    for (int off = 1; off < 64; off <<= 1) {
        int y = __shfl_up(x, off, 64);
        if (lane >= off) x += y;
    }
    if (lane == 63) wsum[wid] = x;
    __syncthreads();
    if (wid == 0 && lane < 16) {
        int w0 = wsum[lane];
#pragma unroll
        for (int off = 1; off < 16; off <<= 1) {
            int y = __shfl_up(w0, off, 16);
            if (lane >= off) w0 += y;
        }
        wsum[lane] = w0;
    }
    __syncthreads();
    int base = (wid > 0) ? wsum[wid - 1] : 0;
    int incl = base + x;
    if (gid < n) out[gid] = incl - v;
    if (threadIdx.x == 1023) bsum[blockIdx.x] = incl;
}

__global__ __launch_bounds__(1024) void k_scan2(int* __restrict__ bsum, int nb)
{
    __shared__ int wsum[16];
    int lane = threadIdx.x & 63, wid = threadIdx.x >> 6;
    int v = (threadIdx.x < nb) ? bsum[threadIdx.x] : 0;
    int x = v;
#pragma unroll
    for (int off = 1; off < 64; off <<= 1) {
        int y = __shfl_up(x, off, 64);
        if (lane >= off) x += y;
    }
    if (lane == 63) wsum[wid] = x;
    __syncthreads();
    if (wid == 0 && lane < 16) {
        int w0 = wsum[lane];
#pragma unroll
        for (int off = 1; off < 16; off <<= 1) {
            int y = __shfl_up(w0, off, 16);
            if (lane >= off) w0 += y;
        }
        wsum[lane] = w0;
    }
    __syncthreads();
    int base = (wid > 0) ? wsum[wid - 1] : 0;
    if (threadIdx.x < nb) bsum[threadIdx.x] = base + x - v;
}

__global__ __launch_bounds__(1024) void k_scan3(int* __restrict__ indptr,
                                                const int* __restrict__ bsum,
                                                int n, int E)
{
    int gid = blockIdx.x * 1024 + threadIdx.x;
    if (gid < n) indptr[gid] += bsum[blockIdx.x];
    if (gid == 0) indptr[n] = E;
}

// ---- MFMA input projection body + fused conv1 score epilogue --------------
template <int CIN>
static __device__ __forceinline__ void in_proj_body(
    short* WT, float* bl, float* FV, int bid,
    const void* __restrict__ X, const void* __restrict__ W, const void* __restrict__ B,
    const float* __restrict__ FVg,
    bf16* __restrict__ Y,
    float* __restrict__ S0, float* __restrict__ S1v, float* __restrict__ S2v,
    int M, int bf)
{
    constexpr int KP = 40;
    for (int i = threadIdx.x; i < 64 * CIN; i += 256) {
        int n = i / CIN, k = i - n * CIN;
        WT[n * KP + k] = f2bs(ldf(W, k * 64 + n, bf));
    }
    if (threadIdx.x < 64) bl[threadIdx.x] = ldf(B, threadIdx.x, bf);
    if (threadIdx.x < 192) FV[threadIdx.x] = FVg[threadIdx.x];   // L2-hot
    __syncthreads();

    int lane = threadIdx.x & 63;
    int wv   = threadIdx.x >> 6;
    int m = lane & 15, quad = lane >> 4;
    int row0 = (bid * 4 + wv) * 16;
    if (row0 >= M) return;

    int arow = row0 + m; if (arow >= M) arow = M - 1;
    short8 a;
#pragma unroll
    for (int j = 0; j < 8; ++j)
        a[j] = f2bs(ldf(X, arow * CIN + quad * 8 + j, bf));

    f32x4 acc[4] = {};
#pragma unroll
    for (int tt = 0; tt < 4; ++tt) {
        short8 bfr = *(const short8*)&WT[((lane & 15) + 16 * tt) * KP + quad * 8];
        acc[tt] = __builtin_amdgcn_mfma_f32_16x16x32_bf16(a, bfr, acc[tt], 0, 0, 0);
    }

    if (CIN == 34) {
        float x32[4], x33[4];
#pragma unroll
        for (int r = 0; r < 4; ++r) {
            int row = row0 + quad * 4 + r; if (row >= M) row = M - 1;
            x32[r] = ldf(X, row * CIN + 32, bf);
            x33[r] = ldf(X, row * CIN + 33, bf);
        }
#pragma unroll
        for (int tt = 0; tt < 4; ++tt) {
            int col = (lane & 15) + 16 * tt;
            float w32 = bs2f(WT[col * KP + 32]);
            float w33 = bs2f(WT[col * KP + 33]);
#pragma unroll
            for (int r = 0; r < 4; ++r)
                acc[tt][r] += x32[r] * w32 + x33[r] * w33;
        }
    }

    float vs[4] = {}, vd[4] = {}, ve[4] = {};
#pragma unroll
    for (int tt = 0; tt < 4; ++tt) {
        int col = (lane & 15) + 16 * tt;
        float bb = bl[col];
        float w0 = FV[col], w1 = FV[64 + col], w2 = FV[128 + col];
#pragma unroll
        for (int r = 0; r < 4; ++r) {
            int row = row0 + quad * 4 + r;
            float v = acc[tt][r] + bb;
            v = v > 0.f ? v : 0.01f * v;
            if (row < M) Y[(size_t)row * 64 + col] = __float2bfloat16(v);
            vs[r] += v * w0; vd[r] += v * w1; ve[r] += v * w2;
        }
    }
#pragma unroll
    for (int off = 1; off < 16; off <<= 1)
#pragma unroll
        for (int r = 0; r < 4; ++r) {
            vs[r] += __shfl_xor(vs[r], off);
            vd[r] += __shfl_xor(vd[r], off);
            ve[r] += __shfl_xor(ve[r], off);
        }
    int c = lane & 15;
    int row = row0 + quad * 4 + (c & 3);
    if (row < M && c < 12) {
        if (c < 4)       S0[row]  = sel4(vs, c & 3);
        else if (c < 8)  S1v[row] = sel4(vd, c & 3);
        else             S2v[row] = sel4(ve, c & 3);
    }
}

// ---- E: bucket scatter ∥ input projections + conv1 scores -----------------
__global__ __launch_bounds__(256) void k_scatter_inproj(
    const int* __restrict__ bb_s, const int* __restrict__ bb_d,
    const int* __restrict__ pp_s, const int* __restrict__ pp_d,
    const int* __restrict__ bp_s, const int* __restrict__ bp_d,
    const int* __restrict__ histS, unsigned* __restrict__ ebuf,
    int E_bb, int E_pp, int E_bp, int NB, int NP, int nbkt, int nblk,
    const void* __restrict__ Xb, const void* __restrict__ Wb, const void* __restrict__ Bb,
    bf16* __restrict__ Yb, int MB,
    const void* __restrict__ Xp, const void* __restrict__ Wp, const void* __restrict__ Bp,
    bf16* __restrict__ Yp, int MP,
    const float* __restrict__ FVg, const int* __restrict__ flag,
    float* __restrict__ ss_bb, float* __restrict__ sd_bb, float* __restrict__ ss_bp,
    float* __restrict__ ss_pp, float* __restrict__ sd_pp, float* __restrict__ sd_bp)
{
    __shared__ short WT[64 * 40];
    __shared__ float bl[64];
    __shared__ float FV[192];
    if ((int)blockIdx.x < nblk) {
        int* cur = (int*)WT;      // 391 ints fit in WT's 5120 B
        for (int i = threadIdx.x; i < nbkt; i += 256)
            cur[i] = histS[(size_t)i * nblk + blockIdx.x];
        __syncthreads();
        int E_all = E_bb + E_pp + E_bp;
        int base = blockIdx.x * CHUNKE;
        int end = base + CHUNKE < E_all ? base + CHUNKE : E_all;
        for (int i = base + threadIdx.x; i < end; i += 256) {
            int s, d;
            if (i < E_bb) { s = bb_s[i]; d = bb_d[i]; }
            else if (i < E_bb + E_pp) { int j = i - E_bb; s = pp_s[j]; d = NB + pp_d[j]; }
            else { int j = i - E_bb - E_pp; s = bp_s[j]; d = NB + NP + bp_d[j]; }
            int p = atomicAdd(&cur[d >> ABITS], 1);
            ebuf[p] = ((unsigned)(d & ((1 << ABITS) - 1)) << 20) | (unsigned)s;
        }
    } else {
        const int bfv = *flag;
        int bid = blockIdx.x - nblk;
        int nbb = (MB + 63) >> 6;
        if (bid < nbb)
            in_proj_body<32>(WT, bl, FV, bid, Xb, Wb, Bb, FVg,
                Yb, ss_bb, sd_bb, ss_bp, MB, bfv);
        else
            in_proj_body<34>(WT, bl, FV, bid - nbb, Xp, Wp, Bp, FVg + 192,
                Yp, ss_pp, sd_pp, sd_bp, MP, bfv);
    }
}

// ---- F: finalize CSR + emit packed (src, w) edge payload ------------------
__global__ __launch_bounds__(256) void k_finalize(
    const unsigned* __restrict__ ebuf, const int* __restrict__ histS,
    int* __restrict__ ip_all, int2* __restrict__ sw,
    const float* __restrict__ ss_bb, const float* __restrict__ sd_bb,
    const float* __restrict__ ss_pp, const float* __restrict__ sd_pp,
    const float* __restrict__ ss_bp, const float* __restrict__ sd_bp,
    int NB, int NP, int NALL, int E_all, int nbkt, int nblk)
{
    __shared__ int h[1 << ABITS];
    __shared__ int pre[1 << ABITS];
    __shared__ int wq[4];
    int b = blockIdx.x;
    int d0 = b << ABITS;
    int nloc = NALL - d0 < (1 << ABITS) ? NALL - d0 : (1 << ABITS);
    int t = threadIdx.x;
    for (int i = t; i < (1 << ABITS); i += 256) h[i] = 0;
    __syncthreads();
    int s0 = histS[(size_t)b * nblk];
    int s1 = histS[(size_t)(b + 1) * nblk];
    for (int i = s0 + t; i < s1; i += 256)
        atomicAdd(&h[ebuf[i] >> 20], 1);
    __syncthreads();
    int v0 = h[2 * t], v1 = h[2 * t + 1];
    int ps = v0 + v1;
    int lane = t & 63, wid = t >> 6;
    int x = ps;
#pragma unroll
    for (int off = 1; off < 64; off <<= 1) {
        int y = __shfl_up(x, off, 64);
        if (lane >= off) x += y;
    }
    if (lane == 63) wq[wid] = x;
    __syncthreads();
    if (t == 0) {
        int a = 0;
#pragma unroll
        for (int w = 0; w < 4; ++w) { int tmp = wq[w]; wq[w] = a; a += tmp; }
    }
    __syncthreads();
    int excl = wq[wid] + x - ps;
    pre[2 * t]     = excl;
    pre[2 * t + 1] = excl + v0;
    __syncthreads();
    for (int i = t; i < nloc; i += 256) ip_all[d0 + i] = s0 + pre[i];
    if (d0 + nloc == NALL && t == 0) ip_all[NALL] = E_all;
    for (int i = t; i < (1 << ABITS); i += 256) h[i] = s0 + pre[i];
    __syncthreads();
    for (int i = s0 + t; i < s1; i += 256) {
        unsigned e = ebuf[i];
        int dl = (int)(e >> 20);
        int src = (int)(e & 0xFFFFFu);
        int p = atomicAdd(&h[dl], 1);
        int d = d0 + dl;
        float ssv, sdv;
        if (d < NB)           { ssv = ss_bb[src]; sdv = sd_bb[d]; }
        else if (d < NB + NP) { ssv = ss_pp[src]; sdv = sd_pp[d - NB]; }
        else                  { ssv = ss_bp[src]; sdv = sd_bp[d - NB - NP]; }
        int2 pk; pk.x = src; pk.y = __float_as_int(__expf(lrelu2(ssv + sdv)));
        sw[p] = pk;
    }
}

// ---- conv1 gather bodies: raw tables, write normalized aggregates ---------
static __device__ __forceinline__ void gather1_body(
    int bid, const int* __restrict__ ip, const int2* __restrict__ sw,
    const float* __restrict__ SS, const float* __restrict__ SD,
    const bf16* __restrict__ HS, bf16* __restrict__ OUT, int M)
{
    int lane = threadIdx.x & 63;
    int half = lane >> 5, hl = lane & 31;
    int d = bid * 4 + (threadIdx.x >> 6);
    if (d >= M) return;
    const u32* H32 = (const u32*)HS;
    float ax = 0.f, ay = 0.f, den = 0.f;
    if (half == 0) {
        float ex = __expf(lrelu2(SS[d] + SD[d]));
        u32 h = H32[(size_t)d * 32 + hl];
        ax = lo16(h) * ex; ay = hi16(h) * ex; den = ex;
    }
    int j1 = ip[d + 1];
    int j = ip[d] + half;
    for (; j + 6 < j1; j += 8) {
        int2 p0 = sw[j], p1 = sw[j + 2], p2 = sw[j + 4], p3 = sw[j + 6];
        u32 h0 = H32[(size_t)p0.x * 32 + hl];
        u32 h1 = H32[(size_t)p1.x * 32 + hl];
        u32 h2 = H32[(size_t)p2.x * 32 + hl];
        u32 h3 = H32[(size_t)p3.x * 32 + hl];
        float e0 = __int_as_float(p0.y), e1 = __int_as_float(p1.y);
        float e2 = __int_as_float(p2.y), e3 = __int_as_float(p3.y);
        ax += lo16(h0) * e0 + lo16(h1) * e1 + lo16(h2) * e2 + lo16(h3) * e3;
        ay += hi16(h0) * e0 + hi16(h1) * e1 + hi16(h2) * e2 + hi16(h3) * e3;
        den += (e0 + e1) + (e2 + e3);
    }
    for (; j < j1; j += 2) {
        int2 p0 = sw[j];
        u32 h0 = H32[(size_t)p0.x * 32 + hl];
        float e0 = __int_as_float(p0.y);
        ax += lo16(h0) * e0; ay += hi16(h0) * e0; den += e0;
    }
    ax += __shfl_xor(ax, 32); ay += __shfl_xor(ay, 32); den += __shfl_xor(den, 32);
    if (half == 0) {
        float inv = 1.f / den;   // self loop -> den > 0
        ((u32*)OUT)[(size_t)d * 32 + hl] = pack2(ax * inv, ay * inv);
    }
}

static __device__ __forceinline__ void gather2_body(
    int bid, const int* __restrict__ ip1, const int2* __restrict__ sw,
    const float* __restrict__ SS1, const float* __restrict__ SD1,
    const bf16* __restrict__ H1T,
    const int* __restrict__ ip2, const bf16* __restrict__ H2T,
    bf16* __restrict__ O1, bf16* __restrict__ O2, int M)
{
    int lane = threadIdx.x & 63;
    int half = lane >> 5, hl = lane & 31;
    int d = bid * 4 + (threadIdx.x >> 6);
    if (d >= M) return;
    const u32* H1 = (const u32*)H1T;
    const u32* H2 = (const u32*)H2T;
    float a1x = 0.f, a1y = 0.f, den1 = 0.f;
    if (half == 0) {
        float ex = __expf(lrelu2(SS1[d] + SD1[d]));
        u32 h = H1[(size_t)d * 32 + hl];
        a1x = lo16(h) * ex; a1y = hi16(h) * ex; den1 = ex;
    }
    int j1 = ip1[d + 1];
    int j = ip1[d] + half;
    for (; j + 6 < j1; j += 8) {
        int2 p0 = sw[j], p1 = sw[j + 2], p2 = sw[j + 4], p3 = sw[j + 6];
        u32 h0 = H1[(size_t)p0.x * 32 + hl];
        u32 h1 = H1[(size_t)p1.x * 32 + hl];
        u32 h2 = H1[(size_t)p2.x * 32 + hl];
        u32 h3 = H1[(size_t)p3.x * 32 + hl];
        float e0 = __int_as_float(p0.y), e1 = __int_as_float(p1.y);
        float e2 = __int_as_float(p2.y), e3 = __int_as_float(p3.y);
        a1x += lo16(h0) * e0 + lo16(h1) * e1 + lo16(h2) * e2 + lo16(h3) * e3;
        a1y += hi16(h0) * e0 + hi16(h1) * e1 + hi16(h2) * e2 + hi16(h3) * e3;
        den1 += (e0 + e1) + (e2 + e3);
    }
    for (; j < j1; j += 2) {
        int2 p0 = sw[j];
        u32 h0 = H1[(size_t)p0.x * 32 + hl];
        float e0 = __int_as_float(p0.y);
        a1x += lo16(h0) * e0; a1y += hi16(h0) * e0; den1 += e0;
    }
    float a2x = 0.f, a2y = 0.f, den2 = 0.f;
    j1 = ip2[d + 1];
    j = ip2[d] + half;
    for (; j + 6 < j1; j += 8) {
        int2 p0 = sw[j], p1 = sw[j + 2], p2 = sw[j + 4], p3 = sw[j + 6];
        u32 h0 = H2[(size_t)p0.x * 32 + hl];
        u32 h1 = H2[(size_t)p1.x * 32 + hl];
        u32 h2 = H2[(size_t)p2.x * 32 + hl];
        u32 h3 = H2[(size_t)p3.x * 32 + hl];
        float e0 = __int_as_float(p0.y), e1 = __int_as_float(p1.y);
        float e2 = __int_as_float(p2.y), e3 = __int_as_float(p3.y);
        a2x += lo16(h0) * e0 + lo16(h1) * e1 + lo16(h2) * e2 + lo16(h3) * e3;
        a2y += hi16(h0) * e0 + hi16(h1) * e1 + hi16(h2) * e2 + hi16(h3) * e3;
        den2 += (e0 + e1) + (e2 + e3);
    }
    for (; j < j1; j += 2) {
        int2 p0 = sw[j];
        u32 h0 = H2[(size_t)p0.x * 32 + hl];
        float e0 = __int_as_float(p0.y);
        a2x += lo16(h0) * e0; a2y += hi16(h0) * e0; den2 += e0;
    }
    a1x += __shfl_xor(a1x, 32); a1y += __shfl_xor(a1y, 32); den1 += __shfl_xor(den1, 32);
    a2x += __shfl_xor(a2x, 32); a2y += __shfl_xor(a2y, 32); den2 += __shfl_xor(den2, 32);
    if (half == 0) {
        float inv1 = 1.f / den1;                       // self loop -> den1 > 0
        float inv2 = den2 > 0.f ? 1.f / den2 : 0.f;
        ((u32*)O1)[(size_t)d * 32 + hl] = pack2(a1x * inv1, a1y * inv1);
        ((u32*)O2)[(size_t)d * 32 + hl] = pack2(a2x * inv2, a2y * inv2);
    }
}

// merged conv1 gathers (raw hb/hp tables)
__global__ __launch_bounds__(256) void k_gather12(
    const int* __restrict__ ip_bb, const int2* __restrict__ sw,
    const float* __restrict__ ss_bb, const float* __restrict__ sd_bb,
    const bf16* __restrict__ hb, bf16* __restrict__ agg_bb, int NB,
    const int* __restrict__ ip_pp, const int* __restrict__ ip_bp,
    const float* __restrict__ ss_pp, const float* __restrict__ sd_pp,
    const bf16* __restrict__ hp,
    bf16* __restrict__ agg_pp, bf16* __restrict__ agg_bp, int NP)
{
    int nbb = (NB + 3) >> 2;
    if ((int)blockIdx.x < nbb)
        gather1_body(blockIdx.x, ip_bb, sw, ss_bb, sd_bb, hb, agg_bb, NB);
    else
        gather2_body(blockIdx.x - nbb, ip_pp, sw, ss_pp, sd_pp, hp,
                     ip_bp, hb, agg_pp, agg_bp, NP);
}

// ---- H: fused conv1-postproj (stage1) + conv2-proj (stage2) ---------------
template <bool D1, bool D2>
static __device__ __forceinline__ void fused_body(
    short* WT1, short* WT2, short* HT, float* bl, int bid,
    const bf16* __restrict__ A1, const bf16* __restrict__ A2,
    const void* W1a, const void* W1b, const void* B1a, const void* B1b,
    const void* W2a, const void* W2b,
    const void* av0, const void* av1, const void* av2,
    bf16* __restrict__ HS,
    float* __restrict__ S0, float* __restrict__ S1v, float* __restrict__ S2v,
    int M, int bf)
{
    constexpr int KP = 72;
    for (int i = threadIdx.x; i < 64 * 64; i += 256) {
        int n = i >> 6, k = i & 63;
        WT1[n * KP + k] = f2bs(ldf(W1a, k * 64 + n, bf));
        if (D1) WT1[(64 + n) * KP + k] = f2bs(ldf(W1b, k * 64 + n, bf));
    }
    for (int i = threadIdx.x; i < 32 * 64; i += 256) {
        int n = i >> 6, k = i & 63;      // n < 32
        WT2[n * KP + k] = f2bs(ldf(W2a, k * 32 + n, bf));
        if (D2) WT2[(32 + n) * KP + k] = f2bs(ldf(W2b, k * 32 + n, bf));
    }
    if (threadIdx.x < 64) {
        float b = ldf(B1a, threadIdx.x, bf);
        if (D1) b += ldf(B1b, threadIdx.x, bf);
        bl[threadIdx.x] = b;
    }
    __syncthreads();

    int lane = threadIdx.x & 63;
    int wv   = threadIdx.x >> 6;
    int m = lane & 15, quad = lane >> 4;
    int row0 = (bid * 4 + wv) * 16;
    bool act = row0 < M;

    const short* A1s = (const short*)A1;
    const short* A2s = (const short*)A2;
    if (act) {
        int arow = row0 + m; if (arow >= M) arow = M - 1;
        f32x4 acc[4] = {};
#pragma unroll
        for (int ks = 0; ks < 2; ++ks) {
            short8 a1 = *(const short8*)&A1s[(size_t)arow * 64 + ks * 32 + quad * 8];
#pragma unroll
            for (int tt = 0; tt < 4; ++tt) {
                short8 bfr = *(const short8*)&WT1[((lane & 15) + 16 * tt) * KP + ks * 32 + quad * 8];
                acc[tt] = __builtin_amdgcn_mfma_f32_16x16x32_bf16(a1, bfr, acc[tt], 0, 0, 0);
            }
            if (D1) {
                short8 a2 = *(const short8*)&A2s[(size_t)arow * 64 + ks * 32 + quad * 8];
#pragma unroll
                for (int tt = 0; tt < 4; ++tt) {
                    short8 bfr = *(const short8*)&WT1[(64 + (lane & 15) + 16 * tt) * KP + ks * 32 + quad * 8];
                    acc[tt] = __builtin_amdgcn_mfma_f32_16x16x32_bf16(a2, bfr, acc[tt], 0, 0, 0);
                }
            }
        }
#pragma unroll
        for (int tt = 0; tt < 4; ++tt) {
            int col = (lane & 15) + 16 * tt;
            float bb = bl[col];
#pragma unroll
            for (int r = 0; r < 4; ++r) {
                float v = acc[tt][r] + bb;
                v = v > 0.f ? v : 0.01f * v;
                HT[(wv * 16 + quad * 4 + r) * 80 + col] = f2bs(v);
            }
        }
    }
    __syncthreads();

    f32x4 acc2[D2 ? 4 : 2] = {};
    if (act) {
        int arow = row0 + m; if (arow >= M) arow = M - 1;
        int al = arow - bid * 64;        // in [0,64)
#pragma unroll
        for (int ks = 0; ks < 2; ++ks) {
            short8 a = *(const short8*)&HT[al * 80 + ks * 32 + quad * 8];
#pragma unroll
            for (int tt = 0; tt < (D2 ? 4 : 2); ++tt) {
                short8 bfr = *(const short8*)&WT2[((lane & 15) + 16 * tt) * KP + ks * 32 + quad * 8];
                acc2[tt] = __builtin_amdgcn_mfma_f32_16x16x32_bf16(a, bfr, acc2[tt], 0, 0, 0);
            }
        }
    }

    float vs[4] = {}, vd[4] = {}, ve[4] = {};
#pragma unroll
    for (int tt = 0; tt < 2; ++tt) {
        int col = (lane & 15) + 16 * tt;
        float a0 = ldf(av0, col, bf);
#pragma unroll
        for (int r = 0; r < 4; ++r) vs[r] += acc2[tt][r] * a0;
        if (D1) {
            float a1 = ldf(av1, col, bf);
#pragma unroll
            for (int r = 0; r < 4; ++r) vd[r] += acc2[tt][r] * a1;
        }
    }
    if (D2) {
#pragma unroll
        for (int tt = 0; tt < 2; ++tt) {
            int col = (lane & 15) + 16 * tt;
            float a2 = ldf(av2, col, bf);
#pragma unroll
            for (int r = 0; r < 4; ++r) ve[r] += acc2[2 + tt][r] * a2;
        }
    }
#pragma unroll
    for (int off = 1; off < 16; off <<= 1)
#pragma unroll
        for (int r = 0; r < 4; ++r) {
            vs[r] += __shfl_xor(vs[r], off);
            if (D1) vd[r] += __shfl_xor(vd[r], off);
            if (D2) ve[r] += __shfl_xor(ve[r], off);
        }
    int c = lane & 15;
    int row = row0 + quad * 4 + (c & 3);
    if (act && row < M) {
        if (c < 4)                    S0[row]  = sel4(vs, c & 3);
        else if (D1 && c < 8)         S1v[row] = sel4(vd, c & 3);
        else if (D2 && c >= 8 && c < 12) S2v[row] = sel4(ve, c & 3);
    }
    if (act) {
#pragma unroll
        for (int tt = 0; tt < 2; ++tt) {
            int col = (lane & 15) + 16 * tt;
#pragma unroll
            for (int r = 0; r < 4; ++r) {
                int row2 = row0 + quad * 4 + r;
                if (row2 < M)
                    HS[(size_t)row2 * 32 + col] = __float2bfloat16(acc2[tt][r]);
            }
        }
    }
}

__global__ __launch_bounds__(256) void k_fused_proj(
    const bf16* __restrict__ agg_pp, const bf16* __restrict__ agg_bp,
    const void* W_pp1, const void* Ws_bp1, const void* b_pp1, const void* b_bp1,
    const void* W_pp2, const void* Wd_bp2,
    const void* as_pp2, const void* ad_pp2, const void* ad_bp2,
    bf16* __restrict__ hs2_pp, float* __restrict__ ss2_pp,
    float* __restrict__ sd2_pp, float* __restrict__ sd2_bp, int MP,
    const bf16* __restrict__ agg_bb, const void* W_bb1, const void* b_bb1,
    const void* Ws_bp2, const void* as_bp2,
    bf16* __restrict__ hs2_bp, float* __restrict__ ss2_bp, int MB,
    const int* __restrict__ flag)
{
    const int bf = *flag;
    __shared__ __align__(16) short WT1[128 * 72];
    __shared__ __align__(16) short WT2[64 * 72];
    __shared__ __align__(16) short HT[64 * 80];
    __shared__ float bl[64];
    int npb = (MP + 63) >> 6;
    if ((int)blockIdx.x < npb)
        fused_body<true, true>(WT1, WT2, HT, bl, blockIdx.x,
            agg_pp, agg_bp, W_pp1, Ws_bp1, b_pp1, b_bp1,
            W_pp2, Wd_bp2, as_pp2, ad_pp2, ad_bp2,
            hs2_pp, ss2_pp, sd2_pp, sd2_bp, MP, bf);
    else
        fused_body<false, false>(WT1, WT2, HT, bl, blockIdx.x - npb,
            agg_bb, nullptr, W_bb1, nullptr, b_bb1, nullptr,
            Ws_bp2, nullptr, as_bp2, nullptr, nullptr,
            hs2_bp, ss2_bp, nullptr, nullptr, MB, bf);
}

// ---- conv2 gather (C=32) + output head, 2 edges/quad unroll ---------------
__global__ __launch_bounds__(256) void k_gather_out(
    const int* __restrict__ ip1, const int2* __restrict__ sw,
    const float* __restrict__ SS1, const float* __restrict__ SD1,
    const bf16* __restrict__ HS1,
    const int* __restrict__ ip2,
    const float* __restrict__ SS2, const float* __restrict__ SD2,
    const bf16* __restrict__ HS2,
    const void* __restrict__ b1, const void* __restrict__ b2,
    const void* __restrict__ Wout, const void* __restrict__ bout,
    void* __restrict__ OUT, int M, const int* __restrict__ flag)
{
    const int bf = *flag;
    int lane = threadIdx.x & 63;
    int q = lane >> 4, hl = lane & 15;
    int d = blockIdx.x * 4 + (threadIdx.x >> 6);
    if (d >= M) return;
    const u32* H1 = (const u32*)HS1;
    const u32* H2 = (const u32*)HS2;
    float sdd = SD1[d];
    float a1x = 0.f, a1y = 0.f, den1 = 0.f;
    if (q == 0) {
        float ex = __expf(lrelu2(SS1[d] + sdd));
        u32 h = H1[(size_t)d * 16 + hl];
        a1x = lo16(h) * ex; a1y = hi16(h) * ex; den1 = ex;
    }
    int j1 = ip1[d + 1];
    int j = ip1[d] + q;
    for (; j + 4 < j1; j += 8) {
        int s0 = sw[j].x, s1 = sw[j + 4].x;
        u32 h0 = H1[(size_t)s0 * 16 + hl];
        u32 h1 = H1[(size_t)s1 * 16 + hl];
        float e0 = __expf(lrelu2(SS1[s0] + sdd));
        float e1 = __expf(lrelu2(SS1[s1] + sdd));
        a1x += lo16(h0) * e0 + lo16(h1) * e1;
        a1y += hi16(h0) * e0 + hi16(h1) * e1;
        den1 += e0 + e1;
    }
    if (j < j1) {
        int s0 = sw[j].x;
        u32 h0 = H1[(size_t)s0 * 16 + hl];
        float e0 = __expf(lrelu2(SS1[s0] + sdd));
        a1x += lo16(h0) * e0; a1y += hi16(h0) * e0; den1 += e0;
    }
    float sdd2 = SD2[d];
    float a2x = 0.f, a2y = 0.f, den2 = 0.f;
    j1 = ip2[d + 1];
    j = ip2[d] + q;
    for (; j + 4 < j1; j += 8) {
        int s0 = sw[j].x, s1 = sw[j + 4].x;
        u32 h0 = H2[(size_t)s0 * 16 + hl];
        u32 h1 = H2[(size_t)s1 * 16 + hl];
        float e0 = __expf(lrelu2(SS2[s0] + sdd2));
        float e1 = __expf(lrelu2(SS2[s1] + sdd2));
        a2x += lo16(h0) * e0 + lo16(h1) * e1;
        a2y += hi16(h0) * e0 + hi16(h1) * e1;
        den2 += e0 + e1;
    }
    if (j < j1) {
        int s0 = sw[j].x;
        u32 h0 = H2[(size_t)s0 * 16 + hl];
        float e0 = __expf(lrelu2(SS2[s0] + sdd2));
        a2x += lo16(h0) * e0; a2y += hi16(h0) * e0; den2 += e0;
    }
    a1x += __shfl_xor(a1x, 16); a1y += __shfl_xor(a1y, 16); den1 += __shfl_xor(den1, 16);
    a2x += __shfl_xor(a2x, 16); a2y += __shfl_xor(a2y, 16); den2 += __shfl_xor(den2, 16);
    a1x += __shfl_xor(a1x, 32); a1y += __shfl_xor(a1y, 32); den1 += __shfl_xor(den1, 32);
    a2x += __shfl_xor(a2x, 32); a2y += __shfl_xor(a2y, 32); den2 += __shfl_xor(den2, 32);
    float inv2 = den2 > 0.f ? 1.f / den2 : 0.f;
    float vx = a1x / den1 + a2x * inv2 + ldf(b1, 2 * hl, bf) + ldf(b2, 2 * hl, bf);
    float vy = a1y / den1 + a2y * inv2 + ldf(b1, 2 * hl + 1, bf) + ldf(b2, 2 * hl + 1, bf);
    vx = vx > 0.f ? vx : 0.01f * vx;
    vy = vy > 0.f ? vy : 0.01f * vy;
    float t = vx * ldf(Wout, 2 * hl, bf) + vy * ldf(Wout, 2 * hl + 1, bf);
#pragma unroll
    for (int off = 1; off < 16; off <<= 1) t += __shfl_xor(t, off);
    if (lane == 0) {
        float r = t + ldf(bout, 0, bf);
        if (bf) ((bf16*)OUT)[d] = __float2bfloat16(r);
        else    ((float*)OUT)[d] = r;
    }
}

// ---------------------------------------------------------------------------
extern "C" void kernel_launch(void* const* d_in, const int* in_sizes, int n_in,
                              void* d_out, int out_size, void* d_ws, size_t ws_size,
                              hipStream_t stream)
{
    const void* x_b = d_in[0];
    const void* x_p = d_in[1];
    const int* ei_bb = (const int*)d_in[2];
    const int* ei_pp = (const int*)d_in[3];
    const int* bp_s  = (const int*)d_in[4];
    const int* bp_d  = (const int*)d_in[5];
    const void *W_in_b = d_in[6],  *b_in_b = d_in[7];
    const void *W_in_p = d_in[8],  *b_in_p = d_in[9];
    const void *W_bb1 = d_in[10], *as_bb1 = d_in[11], *ad_bb1 = d_in[12], *b_bb1 = d_in[13];
    const void *W_pp1 = d_in[14], *as_pp1 = d_in[15], *ad_pp1 = d_in[16], *b_pp1 = d_in[17];
    const void *Ws_bp1 = d_in[18], *Wd_bp1 = d_in[19], *as_bp1 = d_in[20], *ad_bp1 = d_in[21], *b_bp1 = d_in[22];
    // d_in[23..26] = conv2 b->b params: dead code in reference
    const void *W_pp2 = d_in[27], *as_pp2 = d_in[28], *ad_pp2 = d_in[29], *b_pp2 = d_in[30];
    const void *Ws_bp2 = d_in[31], *Wd_bp2 = d_in[32], *as_bp2 = d_in[33], *ad_bp2 = d_in[34], *b_bp2 = d_in[35];
    const void *W_out = d_in[36], *b_out = d_in[37];

    const int NB   = in_sizes[0] / 32;
    const int NP   = in_sizes[1] / 34;
    const int E_bb = in_sizes[2] / 2;
    const int E_pp = in_sizes[3] / 2;
    const int E_bp = in_sizes[4];
    const int E_all = E_bb + E_pp + E_bp;
    const int NALL  = NB + 2 * NP;
    const int* bb_s = ei_bb;  const int* bb_d = ei_bb + E_bb;
    const int* pp_s = ei_pp;  const int* pp_d = ei_pp + E_pp;
    (void)ws_size; (void)n_in; (void)out_size;

    const int nbkt  = (NALL + (1 << ABITS) - 1) >> ABITS;
    const int nblk  = (E_all + CHUNKE - 1) / CHUNKE;
    const int nh    = nbkt * nblk;

    char* base = (char*)d_ws;
    size_t o = 0;
    auto alloc = [&](size_t bytes) { char* p = base + o; o += (bytes + 255) & ~(size_t)255; return p; };

    // --- small persistent ---
    int* flag  = (int*)alloc(256);
    float* FVg = (float*)alloc(6 * 64 * 4);
    int* bsum  = (int*)alloc(1024 * 4);
    int* histM = (int*)alloc((size_t)nh * 4);
    int* histS = (int*)alloc((size_t)(nh + 1) * 4);
    int* ip_all = (int*)alloc((size_t)(NALL + 1) * 4);
    unsigned* ebuf = (unsigned*)alloc((size_t)E_all * 4);
    int2* sw = (int2*)alloc((size_t)E_all * 8);
    float* ss_bb = (float*)alloc((size_t)NB * 4);
    float* sd_bb = (float*)alloc((size_t)NB * 4);
    float* ss_bp = (float*)alloc((size_t)NB * 4);
    float* ss_pp = (float*)alloc((size_t)NP * 4);
    float* sd_pp = (float*)alloc((size_t)NP * 4);
    float* sd_bp = (float*)alloc((size_t)NP * 4);
    float* ss2_bp = ss_bb;   // conv1 scores dead after k_finalize/k_gather12
    float* ss2_pp = ss_pp;
    float* sd2_pp = sd_pp;
    float* sd2_bp = sd_bp;

    // --- feature slots ---
    char* S1 = alloc((size_t)NB * 64 * 2);   // hb -> hs2_bp
    char* S2 = alloc((size_t)NP * 64 * 2);   // hp -> hs2_pp
    char* S3 = alloc((size_t)NB * 64 * 2);   // agg_bb
    char* S5 = alloc((size_t)NP * 64 * 2);   // agg_bp
    char* S6 = alloc((size_t)NP * 64 * 2);   // agg_pp

    bf16* hb     = (bf16*)S1;
    bf16* hp     = (bf16*)S2;
    bf16* agg_bb = (bf16*)S3;
    bf16* agg_bp = (bf16*)S5;
    bf16* agg_pp = (bf16*)S6;
    bf16* hs2_pp = (bf16*)S2;   // overwrites hp (dead after gather12)
    bf16* hs2_bp = (bf16*)S1;   // overwrites hb (dead after gather12)

    auto cdiv = [](int a, int b) { return (a + b - 1) / b; };

    const int* ip_bb = ip_all;
    const int* ip_pp = ip_all + NB;
    const int* ip_bp = ip_all + NB + NP;

    // A. block0: FV + flag; blocks 1..nblk: bucket hist -> histM
    k_fv_hist<<<1 + nblk, 256, 0, stream>>>(
        (const unsigned*)x_b, flag,
        W_bb1, as_bb1, ad_bb1, Ws_bp1, as_bp1,
        W_pp1, as_pp1, ad_pp1, Wd_bp1, ad_bp1, FVg,
        bb_d, pp_d, bp_d, histM, E_bb, E_pp, E_bp, NB, NP, nbkt, nblk);

    // B-D. scan histM -> histS
    int sb1 = cdiv(nh, 1024);
    k_scan1<<<sb1, 1024, 0, stream>>>(histM, histS, bsum, nh);
    k_scan2<<<1, 1024, 0, stream>>>(bsum, sb1);
    k_scan3<<<sb1, 1024, 0, stream>>>(histS, bsum, nh, E_all);

    // E. bucket scatter ∥ input projections + conv1 scores
    k_scatter_inproj<<<nblk + cdiv(NB, 64) + cdiv(NP, 64), 256, 0, stream>>>(
        bb_s, bb_d, pp_s, pp_d, bp_s, bp_d, histS, ebuf,
        E_bb, E_pp, E_bp, NB, NP, nbkt, nblk,
        x_b, W_in_b, b_in_b, hb, NB, x_p, W_in_p, b_in_p, hp, NP,
        FVg, flag, ss_bb, sd_bb, ss_bp, ss_pp, sd_pp, sd_bp);

    // F. finalize CSR + emit packed conv1 edge payload (bucket-local writes)
    k_finalize<<<nbkt, 256, 0, stream>>>(ebuf, histS, ip_all, sw,
                                         ss_bb, sd_bb, ss_pp, sd_pp, ss_bp, sd_bp,
                                         NB, NP, NALL, E_all, nbkt, nblk);

    // G. conv1 gathers over RAW hb/hp (shared table for bb+bp edges)
    k_gather12<<<cdiv(NB, 4) + cdiv(NP, 4), 256, 0, stream>>>(
        ip_bb, sw, ss_bb, sd_bb, hb, agg_bb, NB,
        ip_pp, ip_bp, ss_pp, sd_pp, hp, agg_pp, agg_bp, NP);

    // H. fused conv1-postproj + conv2 projections + conv2 scores
    k_fused_proj<<<cdiv(NP, 64) + cdiv(NB, 64), 256, 0, stream>>>(
        agg_pp, agg_bp, W_pp1, Ws_bp1, b_pp1, b_bp1,
        W_pp2, Wd_bp2, as_pp2, ad_pp2, ad_bp2,
        hs2_pp, ss2_pp, sd2_pp, sd2_bp, NP,
        agg_bb, W_bb1, b_bb1, Ws_bp2, as_bp2,
        hs2_bp, ss2_bp, NB, flag);

    // I. conv2 gather + output head
    k_gather_out<<<cdiv(NP, 4), 256, 0, stream>>>(
        ip_pp, sw, ss2_pp, sd2_pp, hs2_pp,
        ip_bp, ss2_bp, sd2_bp, hs2_bp,
        b_pp2, b_bp2, W_out, b_out, d_out, NP, flag);
}